// Round 1
// baseline (379.951 us; speedup 1.0000x reference)
//
#include <hip/hip_runtime.h>

#define HBV_B  1024
#define HBV_NZ 1e-5f
#define SBUF   (30 * 64)       // one 30-step superchunk buffer (64 lanes)

// ---------------------------------------------------------------------------
// R9: latency-bound on the soil SM recurrence (304 cyc/step measured; 4 hw
// transcendentals x ~60cyc dep latency dominate). Two changes:
//  (a) Replace v_log_f32/v_exp_f32 on the chain with VALU-only polynomials:
//      log2 = exponent-extract + deg-7 poly (8-deep), exp2 = rndne-split +
//      deg-6 poly + v_ldexp (6-deep). New chain ~35 VALU deep ~ 175-210 cyc.
//  (b) Role remap wv>>1 (soil=wv0/wv1) so the two soil waves sit on
//      DIFFERENT SIMDs, each paired with an idle wave: the poly version
//      doubles soil issue count (~65 ops x 2cyc = 130 cyc/step); two soil
//      waves on one SIMD (old wv0/wv4 map) would issue-bind at ~260 cyc.
// Structure otherwise identical to R8: 128 blocks x 512 threads, 30-step
// superchunks, 69 barriers/wave, roles soil/route/idle/snow.
// Phase machine (69 barriers/wave), superchunks sc=0..66 (sc66 = 20 steps):
//   phase p: snow sc p (p<=66) | soil sc p-1 (1<=p<=67) | route sc p-2
//   (2<=p<=68). Buffer parity = sc&1. Sub-blocks of 15 keep FIR ring aligned.
// ---------------------------------------------------------------------------

struct F3 { float x, y, z; };

#define DPP_ADD_ROR(x, ctrl) do {                                              \
    int _r = __builtin_amdgcn_update_dpp(0, __float_as_int(x),                 \
                                         (ctrl), 0xF, 0xF, true);              \
    (x) += __int_as_float(_r);                                                 \
} while (0)

// ---- fast VALU-only transcendentals (replace v_log/v_exp on soil chain) ---
// Returns mul*log2(x) + addc.  Reduction: m in [2/3,4/3) (njuffa constant),
// deg-7 Taylor of log2(1+u)/u on [-1/3,1/3): abs err <= ~6e-6 in log2.
// Critical depth from x: sub,and,sub,sub, {u2,b*}, {q*,u4}, P, fma = 8 VALU.
__device__ __forceinline__ float hbv_log2mad(float x, float mul, float addc)
{
    int   i  = __float_as_int(x);
    int   e  = (i - 0x3f2aaaab) & 0xff800000;
    float u  = __int_as_float(i - e) - 1.0f;        // [-1/3, 1/3)
    float fe = (float)(e >> 23);                    // off-chain path
    float u2 = u * u;
    float b0 = __builtin_fmaf(-0.72134752044f, u, 1.44269504089f);
    float b1 = __builtin_fmaf(-0.36067376022f, u, 0.48089834696f);
    float b2 = __builtin_fmaf(-0.24044917348f, u, 0.28853900818f);
    float b3 = __builtin_fmaf(-0.18033688011f, u, 0.20609929156f);
    float u4 = u2 * u2;
    float q0 = __builtin_fmaf(u2, b1, b0);
    float q1 = __builtin_fmaf(u2, b3, b2);
    float P  = __builtin_fmaf(u4, q1, q0);
    float um = u * mul;                             // off-chain
    float fc = __builtin_fmaf(fe, mul, addc);       // off-chain
    return __builtin_fmaf(um, P, fc);
}

// exp2(y): rndne split, deg-6 Taylor of 2^f on [-0.5,0.5] (rel err ~1.2e-7),
// scale by single v_ldexp_f32 (handles y ~ -160 underflow -> 0 correctly).
// Critical depth: rndne, sub, {f2,b*}, {q*,f4}, P, ldexp = 6 VALU.
__device__ __forceinline__ float hbv_exp2(float y)
{
    float r  = __builtin_rintf(y);
    float f  = y - r;
    int   iy = (int)r;                              // off-chain path
    float f2 = f * f;
    float b0 = __builtin_fmaf(0.69314718056f, f, 1.0f);
    float b1 = __builtin_fmaf(0.05550410866f, f, 0.24022650696f);
    float b2 = __builtin_fmaf(0.00133335581f, f, 0.00961812911f);
    float f4 = f2 * f2;
    float q0 = __builtin_fmaf(f2, b1, b0);
    float q1 = __builtin_fmaf(f2, 0.00015403530f, b2);
    float P  = __builtin_fmaf(f4, q1, q0);
    return __builtin_amdgcn_ldexpf(P, iy);
}

// ---- soil step: R8 math with poly transcendentals on the chain ------------
#define SOIL_STEP(s, rt_, lp_, qdst) do {                                      \
    float rt   = (rt_);                                                        \
    float lp   = (lp_);                                                        \
    float cpet = lp + nBEloglpfc;                                              \
    float CSLZ = parC * SLZ;                                                   \
    float c1   = __builtin_fmaf(-CSLZ, invFC, 1.0f);                           \
    float SMrt = SM + rt;                                                      \
    /* ---- cross-step critical chain ---- */                                  \
    float y1  = hbv_log2mad(SM, parBETA, nBlogFC);                             \
    float sw  = fminf(hbv_exp2(y1), 1.0f);          /* >=0 automatic */        \
    float SM1 = __builtin_fmaf(-rt, sw, SMrt);                                 \
    float SM2 = fminf(SM1, parFC);                                             \
    float SM3 = __builtin_fmaf(SM2, c1, CSLZ);                                 \
    float eef = fminf(hbv_log2mad(SM3, parBETAET, cpet), lp);                  \
    float PETef = hbv_exp2(eef);                                               \
    SM = fmaxf(SM3 - PETef, HBV_NZ);                                           \
    /* ---- off-chain: SUZ/SLZ/Q ---- */                                       \
    float U_ = __builtin_fmaf(rt, sw, SM1 - SM2);   /* recharge+excess */      \
    float S_ = SUZ + U_;                                                       \
    float P_ = fminf(S_, parPERC);                                             \
    float A_ = S_ - P_;                                                        \
    float B_ = fminf(A_, __builtin_fmaf(K0c, A_, K0UZL));                      \
    SUZ = K1c * B_;                                                            \
    float L_ = SLZ - (SM3 - SM2) + P_;                                         \
    SLZ = K2c * L_;                                                            \
    (qdst)[(s) * 64] = __builtin_fmaf(parK2, L_, A_ - SUZ);                    \
} while (0)

// One 15-or-5-step sub-block: stage LDS -> registers, run steps.
#define SOIL_HALF(nn, ofs) do {                                                \
    const float* rs = &rtS[set][(ofs)];                                        \
    const float* ls = &lpS[set][(ofs)];                                        \
    float* qd = &qS[set][(ofs)];                                               \
    float rr[15], lpv[15];                                                     \
    _Pragma("unroll")                                                          \
    for (int k_ = 0; k_ < (nn); ++k_) {                                        \
        rr[k_]  = rs[k_ * 64];                                                 \
        lpv[k_] = ls[k_ * 64];                                                 \
    }                                                                          \
    _Pragma("unroll")                                                          \
    for (int s_ = 0; s_ < (nn); ++s_) SOIL_STEP(s_, rr[s_], lpv[s_], qd);      \
} while (0)

// ---- snow: forcing load + forcing-only recurrence -> rt, log2(PET) --------
#define SNOW_HALF(nn, tb, ofs) do {                                            \
    float Pf[15], Tf[15], Ef[15];                                              \
    _Pragma("unroll")                                                          \
    for (int k_ = 0; k_ < (nn); ++k_) {                                        \
        F3 f = xb3[(size_t)((tb) + k_) * HBV_B];                               \
        Pf[k_] = f.x; Tf[k_] = f.y; Ef[k_] = f.z;                              \
    }                                                                          \
    float* rd = &rtS[set][(ofs)];                                              \
    float* ld = &lpS[set][(ofs)];                                              \
    _Pragma("unroll")                                                          \
    for (int s_ = 0; s_ < (nn); ++s_) {                                        \
        float Pm = Pf[s_], Tc = Tf[s_];                                        \
        float rain = (Tc >= parTT) ? Pm : 0.0f;                                \
        SNW += Pm - rain;                                                      \
        float melt = fminf(fmaxf(__builtin_fmaf(parCFMAX, Tc, negCT), 0.0f),   \
                           SNW);                                               \
        MLT += melt; SNW -= melt;                                              \
        float rfz = fminf(fmaxf(__builtin_fmaf(-CFRC, Tc, CFRCTT), 0.0f),      \
                          MLT);                                                \
        SNW += rfz; MLT -= rfz;                                                \
        float tosoil = fmaxf(__builtin_fmaf(-parCWH, SNW, MLT), 0.0f);         \
        MLT -= tosoil;                                                         \
        rd[s_ * 64] = rain + tosoil;                                           \
        ld[s_ * 64] = __builtin_amdgcn_logf(Ef[s_]);                           \
    }                                                                          \
} while (0)

// ---- route: LDS -> 15-tap FIR ring -> DPP mean over m -> store ------------
// (tb) is always a multiple of 15, so ring slot == local index s_.
#define ROUTE_HALF(nn, tb, ofs) do {                                           \
    const float* qsrc = &qS[set][(ofs)];                                       \
    float qq[15];                                                              \
    _Pragma("unroll")                                                          \
    for (int k_ = 0; k_ < (nn); ++k_) qq[k_] = qsrc[k_ * 64];                  \
    _Pragma("unroll")                                                          \
    for (int s_ = 0; s_ < (nn); ++s_) {                                        \
        q[s_] = qq[s_];                                                        \
        float qr = 0.0f;                                                       \
        _Pragma("unroll")                                                      \
        for (int k_ = 0; k_ < 15; ++k_)                                        \
            qr += w[k_] * q[(s_ - k_ + 15) % 15];                              \
        DPP_ADD_ROR(qr, 0x128);                                                \
        DPP_ADD_ROR(qr, 0x124);                                                \
        DPP_ADD_ROR(qr, 0x122);                                                \
        DPP_ADD_ROR(qr, 0x121);                                                \
        if (m == 0) out[(size_t)((tb) + s_) * HBV_B + b] = qr;                 \
    }                                                                          \
} while (0)

__global__ __launch_bounds__(512, 1)
void hbv_smt_kernel(const float* __restrict__ x_phy,   // (2000, 1024, 3)
                    const float* __restrict__ ps,      // (1024, 288)
                    float* __restrict__ out)           // (2000, 1024)
{
    const int lane = (int)threadIdx.x & 63;
    const int wv   = (int)threadIdx.x >> 6;
    const int set  = wv & 1;                  // 0: cells +0, 1: cells +512
    const int role = wv >> 1;                 // 0 soil, 1 route, 2 idle, 3 snow
    // SIMD pairing (wave i -> SIMD i%4): soil(wv0/1) pairs with idle(wv4/5);
    // route(wv2/3) pairs with snow(wv6/7). Keeps the chain SIMDs issue-quiet.
    const int b    = blockIdx.x * 4 + (lane >> 4) + set * 512;
    const int m    = lane & 15;

    __shared__ float rtS[2][2 * SBUF];   // snow -> soil : rain+tosoil
    __shared__ float lpS[2][2 * SBUF];   // snow -> soil : log2(PET)
    __shared__ float qS [2][2 * SBUF];   // soil -> route: Qsim

    const float* __restrict__ pb = ps + (size_t)b * 288;

    if (role == 0) {
        // --------------------------- SOIL ----------------------------------
        const float parBETA   = 1.0f   + pb[ 0*16 + m] * 5.0f;
        const float parFC     = 50.0f  + pb[ 1*16 + m] * 950.0f;
        const float parK0     = 0.05f  + pb[ 2*16 + m] * 0.85f;
        const float parK1     = 0.01f  + pb[ 3*16 + m] * 0.49f;
        const float parK2     = 0.001f + pb[ 4*16 + m] * 0.199f;
        const float parLP     = 0.2f   + pb[ 5*16 + m] * 0.8f;
        const float parPERC   =          pb[ 6*16 + m] * 10.0f;
        const float parUZL    =          pb[ 7*16 + m] * 100.0f;
        const float parBETAET = 0.3f   + pb[12*16 + m] * 4.7f;
        const float parC      =          pb[13*16 + m];
        const float invFC  = 1.0f / parFC;
        const float K0c    = 1.0f - parK0;
        const float K0UZL  = parK0 * parUZL;
        const float K1c    = 1.0f - parK1;
        const float K2c    = 1.0f - parK2;
        const float nBlogFC    = -parBETA   * __builtin_amdgcn_logf(parFC);
        const float nBEloglpfc = -parBETAET * __builtin_amdgcn_logf(parLP * parFC);

        float SM = HBV_NZ, SUZ = HBV_NZ, SLZ = HBV_NZ;

        __syncthreads();                                  // phase 0
#pragma unroll 1
        for (int sc = 0; sc < 66; ++sc) {                 // phases 1..66
            const int po = (sc & 1) * SBUF + lane;
            SOIL_HALF(15, po);
            SOIL_HALF(15, po + 15 * 64);
            __syncthreads();
        }
        // sc=66 (20 steps, parity 0): phase 67
        SOIL_HALF(15, lane);
        SOIL_HALF(5, lane + 15 * 64);
        __syncthreads();
        __syncthreads();                                  // phase 68
        // 69 barriers.
    } else if (role == 3) {
        // --------------------------- SNOW ----------------------------------
        const float parTT    = -2.5f + pb[ 8*16 + m] * 5.0f;
        const float parCFMAX = 0.5f  + pb[ 9*16 + m] * 9.5f;
        const float parCFR   =         pb[10*16 + m] * 0.1f;
        const float parCWH   =         pb[11*16 + m] * 0.2f;
        const float CFRC   = parCFR * parCFMAX;
        const float negCT  = -parCFMAX * parTT;
        const float CFRCTT =  CFRC * parTT;
        float SNW = HBV_NZ, MLT = HBV_NZ;
        const F3* __restrict__ xb3 = (const F3*)x_phy + b;

#pragma unroll 1
        for (int sc = 0; sc < 66; ++sc) {                 // phases 0..65
            const int po = (sc & 1) * SBUF + lane;
            SNOW_HALF(15, sc * 30,      po);
            SNOW_HALF(15, sc * 30 + 15, po + 15 * 64);
            __syncthreads();
        }
        // sc=66: phase 66
        SNOW_HALF(15, 1980, lane);
        SNOW_HALF(5, 1995, lane + 15 * 64);
        __syncthreads();
        __syncthreads();                                  // phase 67
        __syncthreads();                                  // phase 68
        // 69 barriers.
    } else if (role == 1) {
        // --------------------------- ROUTE ---------------------------------
        const float rout_a = pb[256 + m]      * 2.9f;
        const float rout_b = pb[256 + 16 + m] * 6.5f;
        // w[k] ∝ t_k^(a-1) exp(-t_k/theta); Gamma/theta^a cancels under
        // normalization; pre-scaled by 1/16 for the mean over m.
        const float aa    = fmaxf(rout_a, 0.0f) + 0.1f;
        const float theta = fmaxf(rout_b, 0.0f) + 0.5f;
        const float am1   = aa - 1.0f;
        const float nit   = -1.4426950408889634f / theta;
        float w[15];
        float wsum = 0.0f;
#pragma unroll
        for (int k = 0; k < 15; ++k) {
            float tk = (float)k + 0.5f;
            float e  = am1 * __builtin_amdgcn_logf(tk) + nit * tk;
            w[k] = __builtin_amdgcn_exp2f(e);
            wsum += w[k];
        }
        const float wscale = 1.0f / (16.0f * wsum);
#pragma unroll
        for (int k = 0; k < 15; ++k) w[k] *= wscale;
        float q[15];
#pragma unroll
        for (int k = 0; k < 15; ++k) q[k] = 0.0f;

        __syncthreads();                                  // phase 0
        __syncthreads();                                  // phase 1
#pragma unroll 1
        for (int sc = 0; sc < 66; ++sc) {                 // phases 2..67
            const int po = (sc & 1) * SBUF + lane;
            ROUTE_HALF(15, sc * 30,      po);
            ROUTE_HALF(15, sc * 30 + 15, po + 15 * 64);
            __syncthreads();
        }
        // sc=66: phase 68
        ROUTE_HALF(15, 1980, lane);
        ROUTE_HALF(5, 1995, lane + 15 * 64);
        __syncthreads();
        // 69 barriers.
    } else {
        // --------------------------- IDLER ---------------------------------
#pragma unroll 1
        for (int p = 0; p < 69; ++p) __syncthreads();
    }
}

extern "C" void kernel_launch(void* const* d_in, const int* in_sizes, int n_in,
                              void* d_out, int out_size, void* d_ws, size_t ws_size,
                              hipStream_t stream) {
    const float* x_phy = (const float*)d_in[0];   // (2000,1024,3) fp32
    const float* ps    = (const float*)d_in[1];   // (1024,288)    fp32
    float* out         = (float*)d_out;           // (2000,1024)   fp32

    // 128 blocks x 512 threads (8 waves, 2/SIMD). Wall = 2000 x soil chain;
    // chain now ~35 VALU deep (poly log2/exp2), soil waves on separate SIMDs.
    hbv_smt_kernel<<<128, 512, 0, stream>>>(x_phy, ps, out);
}

// Round 2
// 292.559 us; speedup vs baseline: 1.2987x; 1.2987x over previous
//
#include <hip/hip_runtime.h>

#define HBV_B  1024
#define HBV_NZ 1e-5f
#define SBUF   (45 * 64)       // one 45-step superchunk buffer (64 lanes)

// ---------------------------------------------------------------------------
// R10 = R8 structure (hw transcendentals; poly swap in R9 regressed: measured
// trans dep ~50-65 cyc ~= 8-deep VALU poly, and +45 instr/step cost ~2cyc ea)
// + two exact trims:
//  (a) ET pow: evapfactor = clip01((SM3/(LP*FC))^BETAET) -> ef =
//      clamp01(exp2(BETAET*log2(SM3)+c)) folds the clip into v_exp_f32's
//      output clamp; SM' = max(fma(-PETm, ef, SM3), NZ). Deletes on-chain
//      min(eef,lp) (~7 cyc) and the cpet add; snow passes RAW PET (no log).
//  (b) 45-step superchunks: barriers 69 -> 47 (LDS 138240 B <= 160 KiB).
// Model: wall = 2000 x soil chain L; L = 4 trans (~55 cyc dep each) + 7 VALU
// (~6 cyc) ~= 260; measured R8 304 cyc/step incl. issue. Chains are serial:
// occupancy/interleave CANNOT compress L - only chain algebra can.
// Roles (wv&3): 0 soil, 1 route, 2 snow, 3 idle; set = wv>>2 (cells +512).
// Phase machine (47 barriers/wave), superchunks sc=0..44 (sc44 = 20 steps):
//   phase p: snow sc p (p<=44) | soil sc p-1 (1<=p<=45) | route sc p-2
//   (2<=p<=46). Buffer parity = sc&1. Sub-blocks of 15 keep FIR ring aligned.
// ---------------------------------------------------------------------------

struct F3 { float x, y, z; };

#define DPP_ADD_ROR(x, ctrl) do {                                              \
    int _r = __builtin_amdgcn_update_dpp(0, __float_as_int(x),                 \
                                         (ctrl), 0xF, 0xF, true);              \
    (x) += __int_as_float(_r);                                                 \
} while (0)

// ---- soil step: hw trans chain, both exp2 clamps folded -------------------
#define SOIL_STEP(s, rt_, pet_, qdst) do {                                     \
    float rt   = (rt_);                                                        \
    float PETm = (pet_);                                                       \
    float CSLZ = parC * SLZ;                                                   \
    float c1   = __builtin_fmaf(-CSLZ, invFC, 1.0f);                           \
    float SMrt = SM + rt;                                                      \
    /* ---- cross-step critical chain ---- */                                  \
    float lSM = __builtin_amdgcn_logf(SM);                                     \
    float esw = __builtin_fmaf(parBETA, lSM, nBlogFC);                         \
    float swr = __builtin_amdgcn_exp2f(esw);                                   \
    float sw  = fminf(fmaxf(swr, 0.0f), 1.0f);   /* -> v_exp clamp mod */      \
    float SM1 = __builtin_fmaf(-rt, sw, SMrt);                                 \
    float SM2 = fminf(SM1, parFC);                                             \
    float SM3 = __builtin_fmaf(SM2, c1, CSLZ);                                 \
    float lS3 = __builtin_amdgcn_logf(SM3);                                    \
    float eef = __builtin_fmaf(parBETAET, lS3, nBEloglpfc);                    \
    float efr = __builtin_amdgcn_exp2f(eef);                                   \
    float ef  = fminf(fmaxf(efr, 0.0f), 1.0f);   /* -> v_exp clamp mod */      \
    SM = fmaxf(__builtin_fmaf(-PETm, ef, SM3), HBV_NZ);                        \
    /* ---- off-chain: SUZ/SLZ/Q ---- */                                       \
    float U_ = __builtin_fmaf(rt, sw, SM1 - SM2);   /* recharge+excess */      \
    float S_ = SUZ + U_;                                                       \
    float P_ = fminf(S_, parPERC);                                             \
    float A_ = S_ - P_;                                                        \
    float B_ = fminf(A_, __builtin_fmaf(K0c, A_, K0UZL));                      \
    SUZ = K1c * B_;                                                            \
    float L_ = SLZ - (SM3 - SM2) + P_;                                         \
    SLZ = K2c * L_;                                                            \
    (qdst)[(s) * 64] = __builtin_fmaf(parK2, L_, A_ - SUZ);                    \
} while (0)

// One 15-or-5-step sub-block: stage LDS -> registers, run steps.
#define SOIL_HALF(nn, ofs) do {                                                \
    const float* rs = &rtS[set][(ofs)];                                        \
    const float* es = &petS[set][(ofs)];                                       \
    float* qd = &qS[set][(ofs)];                                               \
    float rr[15], pv[15];                                                      \
    _Pragma("unroll")                                                          \
    for (int k_ = 0; k_ < (nn); ++k_) {                                        \
        rr[k_] = rs[k_ * 64];                                                  \
        pv[k_] = es[k_ * 64];                                                  \
    }                                                                          \
    _Pragma("unroll")                                                          \
    for (int s_ = 0; s_ < (nn); ++s_) SOIL_STEP(s_, rr[s_], pv[s_], qd);       \
} while (0)

// ---- snow: forcing load + forcing-only recurrence -> rt, raw PET ----------
#define SNOW_HALF(nn, tb, ofs) do {                                            \
    float Pf[15], Tf[15], Ef[15];                                              \
    _Pragma("unroll")                                                          \
    for (int k_ = 0; k_ < (nn); ++k_) {                                        \
        F3 f = xb3[(size_t)((tb) + k_) * HBV_B];                               \
        Pf[k_] = f.x; Tf[k_] = f.y; Ef[k_] = f.z;                              \
    }                                                                          \
    float* rd = &rtS[set][(ofs)];                                              \
    float* ed = &petS[set][(ofs)];                                             \
    _Pragma("unroll")                                                          \
    for (int s_ = 0; s_ < (nn); ++s_) {                                        \
        float Pm = Pf[s_], Tc = Tf[s_];                                        \
        float rain = (Tc >= parTT) ? Pm : 0.0f;                                \
        SNW += Pm - rain;                                                      \
        float melt = fminf(fmaxf(__builtin_fmaf(parCFMAX, Tc, negCT), 0.0f),   \
                           SNW);                                               \
        MLT += melt; SNW -= melt;                                              \
        float rfz = fminf(fmaxf(__builtin_fmaf(-CFRC, Tc, CFRCTT), 0.0f),      \
                          MLT);                                                \
        SNW += rfz; MLT -= rfz;                                                \
        float tosoil = fmaxf(__builtin_fmaf(-parCWH, SNW, MLT), 0.0f);         \
        MLT -= tosoil;                                                         \
        rd[s_ * 64] = rain + tosoil;                                           \
        ed[s_ * 64] = Ef[s_];                                                  \
    }                                                                          \
} while (0)

// ---- route: LDS -> 15-tap FIR ring -> DPP mean over m -> store ------------
// (tb) is always a multiple of 15, so ring slot == local index s_.
#define ROUTE_HALF(nn, tb, ofs) do {                                           \
    const float* qsrc = &qS[set][(ofs)];                                       \
    float qq[15];                                                              \
    _Pragma("unroll")                                                          \
    for (int k_ = 0; k_ < (nn); ++k_) qq[k_] = qsrc[k_ * 64];                  \
    _Pragma("unroll")                                                          \
    for (int s_ = 0; s_ < (nn); ++s_) {                                        \
        q[s_] = qq[s_];                                                        \
        float qr = 0.0f;                                                       \
        _Pragma("unroll")                                                      \
        for (int k_ = 0; k_ < 15; ++k_)                                        \
            qr += w[k_] * q[(s_ - k_ + 15) % 15];                              \
        DPP_ADD_ROR(qr, 0x128);                                                \
        DPP_ADD_ROR(qr, 0x124);                                                \
        DPP_ADD_ROR(qr, 0x122);                                                \
        DPP_ADD_ROR(qr, 0x121);                                                \
        if (m == 0) out[(size_t)((tb) + s_) * HBV_B + b] = qr;                 \
    }                                                                          \
} while (0)

__global__ __launch_bounds__(512, 1)
void hbv_smt_kernel(const float* __restrict__ x_phy,   // (2000, 1024, 3)
                    const float* __restrict__ ps,      // (1024, 288)
                    float* __restrict__ out)           // (2000, 1024)
{
    const int lane = (int)threadIdx.x & 63;
    const int wv   = (int)threadIdx.x >> 6;
    const int set  = wv >> 2;                 // 0: cells +0, 1: cells +512
    const int role = wv & 3;                  // 0 soil, 1 route, 2 snow, 3 idle
    const int b    = blockIdx.x * 4 + (lane >> 4) + set * 512;
    const int m    = lane & 15;

    __shared__ float rtS [2][2 * SBUF];  // snow -> soil : rain+tosoil
    __shared__ float petS[2][2 * SBUF];  // snow -> soil : raw PET
    __shared__ float qS  [2][2 * SBUF];  // soil -> route: Qsim

    const float* __restrict__ pb = ps + (size_t)b * 288;

    if (role == 0) {
        // --------------------------- SOIL ----------------------------------
        const float parBETA   = 1.0f   + pb[ 0*16 + m] * 5.0f;
        const float parFC     = 50.0f  + pb[ 1*16 + m] * 950.0f;
        const float parK0     = 0.05f  + pb[ 2*16 + m] * 0.85f;
        const float parK1     = 0.01f  + pb[ 3*16 + m] * 0.49f;
        const float parK2     = 0.001f + pb[ 4*16 + m] * 0.199f;
        const float parLP     = 0.2f   + pb[ 5*16 + m] * 0.8f;
        const float parPERC   =          pb[ 6*16 + m] * 10.0f;
        const float parUZL    =          pb[ 7*16 + m] * 100.0f;
        const float parBETAET = 0.3f   + pb[12*16 + m] * 4.7f;
        const float parC      =          pb[13*16 + m];
        const float invFC  = 1.0f / parFC;
        const float K0c    = 1.0f - parK0;
        const float K0UZL  = parK0 * parUZL;
        const float K1c    = 1.0f - parK1;
        const float K2c    = 1.0f - parK2;
        const float nBlogFC    = -parBETA   * __builtin_amdgcn_logf(parFC);
        const float nBEloglpfc = -parBETAET * __builtin_amdgcn_logf(parLP * parFC);

        float SM = HBV_NZ, SUZ = HBV_NZ, SLZ = HBV_NZ;

        __syncthreads();                                  // phase 0
#pragma unroll 1
        for (int sc = 0; sc < 44; ++sc) {                 // phases 1..44
            const int po = (sc & 1) * SBUF + lane;
            SOIL_HALF(15, po);
            SOIL_HALF(15, po + 15 * 64);
            SOIL_HALF(15, po + 30 * 64);
            __syncthreads();
        }
        // sc=44 (20 steps, parity 0): phase 45
        SOIL_HALF(15, lane);
        SOIL_HALF(5, lane + 15 * 64);
        __syncthreads();
        __syncthreads();                                  // phase 46
        // 47 barriers.
    } else if (role == 2) {
        // --------------------------- SNOW ----------------------------------
        const float parTT    = -2.5f + pb[ 8*16 + m] * 5.0f;
        const float parCFMAX = 0.5f  + pb[ 9*16 + m] * 9.5f;
        const float parCFR   =         pb[10*16 + m] * 0.1f;
        const float parCWH   =         pb[11*16 + m] * 0.2f;
        const float CFRC   = parCFR * parCFMAX;
        const float negCT  = -parCFMAX * parTT;
        const float CFRCTT =  CFRC * parTT;
        float SNW = HBV_NZ, MLT = HBV_NZ;
        const F3* __restrict__ xb3 = (const F3*)x_phy + b;

#pragma unroll 1
        for (int sc = 0; sc < 44; ++sc) {                 // phases 0..43
            const int po = (sc & 1) * SBUF + lane;
            SNOW_HALF(15, sc * 45,      po);
            SNOW_HALF(15, sc * 45 + 15, po + 15 * 64);
            SNOW_HALF(15, sc * 45 + 30, po + 30 * 64);
            __syncthreads();
        }
        // sc=44: phase 44
        SNOW_HALF(15, 1980, lane);
        SNOW_HALF(5, 1995, lane + 15 * 64);
        __syncthreads();
        __syncthreads();                                  // phase 45
        __syncthreads();                                  // phase 46
        // 47 barriers.
    } else if (role == 1) {
        // --------------------------- ROUTE ---------------------------------
        const float rout_a = pb[256 + m]      * 2.9f;
        const float rout_b = pb[256 + 16 + m] * 6.5f;
        // w[k] ∝ t_k^(a-1) exp(-t_k/theta); Gamma/theta^a cancels under
        // normalization; pre-scaled by 1/16 for the mean over m.
        const float aa    = fmaxf(rout_a, 0.0f) + 0.1f;
        const float theta = fmaxf(rout_b, 0.0f) + 0.5f;
        const float am1   = aa - 1.0f;
        const float nit   = -1.4426950408889634f / theta;
        float w[15];
        float wsum = 0.0f;
#pragma unroll
        for (int k = 0; k < 15; ++k) {
            float tk = (float)k + 0.5f;
            float e  = am1 * __builtin_amdgcn_logf(tk) + nit * tk;
            w[k] = __builtin_amdgcn_exp2f(e);
            wsum += w[k];
        }
        const float wscale = 1.0f / (16.0f * wsum);
#pragma unroll
        for (int k = 0; k < 15; ++k) w[k] *= wscale;
        float q[15];
#pragma unroll
        for (int k = 0; k < 15; ++k) q[k] = 0.0f;

        __syncthreads();                                  // phase 0
        __syncthreads();                                  // phase 1
#pragma unroll 1
        for (int sc = 0; sc < 44; ++sc) {                 // phases 2..45
            const int po = (sc & 1) * SBUF + lane;
            ROUTE_HALF(15, sc * 45,      po);
            ROUTE_HALF(15, sc * 45 + 15, po + 15 * 64);
            ROUTE_HALF(15, sc * 45 + 30, po + 30 * 64);
            __syncthreads();
        }
        // sc=44: phase 46
        ROUTE_HALF(15, 1980, lane);
        ROUTE_HALF(5, 1995, lane + 15 * 64);
        __syncthreads();
        // 47 barriers.
    } else {
        // --------------------------- IDLER ---------------------------------
#pragma unroll 1
        for (int p = 0; p < 47; ++p) __syncthreads();
    }
}

extern "C" void kernel_launch(void* const* d_in, const int* in_sizes, int n_in,
                              void* d_out, int out_size, void* d_ws, size_t ws_size,
                              hipStream_t stream) {
    const float* x_phy = (const float*)d_in[0];   // (2000,1024,3) fp32
    const float* ps    = (const float*)d_in[1];   // (1024,288)    fp32
    float* out         = (float*)d_out;           // (2000,1024)   fp32

    // 128 blocks x 512 threads (8 waves, 2/SIMD). Wall = 2000 x soil chain;
    // chain trimmed to 4 trans + 7 VALU (ET min folded into exp clamp);
    // 45-step superchunks cut barriers 69 -> 47.
    hbv_smt_kernel<<<128, 512, 0, stream>>>(x_phy, ps, out);
}

// Round 3
// 222.113 us; speedup vs baseline: 1.7106x; 1.3172x over previous
//
#include <hip/hip_runtime.h>

#define HBV_B  1024
#define HBV_NZ 1e-5f
#define SBUF   (30 * 64)       // one 30-step superchunk buffer (64 lanes)

// ---------------------------------------------------------------------------
// R11 = R8's proven 30-chunk/69-barrier phase machine + R10's exact ET chain
// trim + solo-SIMD soil placement.
//  - R10 post-mortem: 45-step superchunks (3 sub-blocks/phase, VGPR 88->104)
//    REGRESSED ~25 cyc/step; the ET trim itself is exact (absmax 0.0078125).
//    Reverted to 30-chunks.
//  - ET trim (kept): evapfactor = clip01((SM3/(LP*FC))^BETAET) -> ef =
//    clamp01(exp2(BETAET*log2(SM3)+c)) folds the clip into v_exp_f32's
//    output clamp; SM' = max(fma(-PETm, ef, SM3), NZ). Snow passes RAW PET.
//    Chain: 4 trans + 7 VALU ~= 289 cyc floor (R8 was 4T+9V = 304 measured).
//  - NEW: 256 blocks x 256 threads, ONE set per block; wv0=soil wv1=route
//    wv2=snow wv3=idle -> one wave per SIMD (wave i -> SIMD i%4). The soil
//    chain now owns SIMD0 with zero issue competition (R8 had both soil
//    waves on SIMD0). 36 KB dynamic LDS pads the group segment past 80 KB
//    so only 1 block/CU can ever be resident (no second soil wave on SIMD0).
// Model: wall = 2000 x serial soil-chain latency; chains are per-(cell,mul)
// and all 16384 run in parallel already - only chain algebra/issue can help.
// Phase machine (69 barriers/wave), superchunks sc=0..66 (sc66 = 20 steps):
//   phase p: snow sc p (p<=66) | soil sc p-1 (1<=p<=67) | route sc p-2
//   (2<=p<=68). Buffer parity = sc&1. Sub-blocks of 15 keep FIR ring aligned.
// ---------------------------------------------------------------------------

struct F3 { float x, y, z; };

#define DPP_ADD_ROR(x, ctrl) do {                                              \
    int _r = __builtin_amdgcn_update_dpp(0, __float_as_int(x),                 \
                                         (ctrl), 0xF, 0xF, true);              \
    (x) += __int_as_float(_r);                                                 \
} while (0)

// ---- soil step: hw trans chain, both exp2 clamps folded (4T + 7V deep) ----
#define SOIL_STEP(s, rt_, pet_, qdst) do {                                     \
    float rt   = (rt_);                                                        \
    float PETm = (pet_);                                                       \
    float CSLZ = parC * SLZ;                                                   \
    float c1   = __builtin_fmaf(-CSLZ, invFC, 1.0f);                           \
    float SMrt = SM + rt;                                                      \
    /* ---- cross-step critical chain ---- */                                  \
    float lSM = __builtin_amdgcn_logf(SM);                                     \
    float esw = __builtin_fmaf(parBETA, lSM, nBlogFC);                         \
    float swr = __builtin_amdgcn_exp2f(esw);                                   \
    float sw  = fminf(fmaxf(swr, 0.0f), 1.0f);   /* -> v_exp clamp mod */      \
    float SM1 = __builtin_fmaf(-rt, sw, SMrt);                                 \
    float SM2 = fminf(SM1, parFC);                                             \
    float SM3 = __builtin_fmaf(SM2, c1, CSLZ);                                 \
    float lS3 = __builtin_amdgcn_logf(SM3);                                    \
    float eef = __builtin_fmaf(parBETAET, lS3, nBEloglpfc);                    \
    float efr = __builtin_amdgcn_exp2f(eef);                                   \
    float ef  = fminf(fmaxf(efr, 0.0f), 1.0f);   /* -> v_exp clamp mod */      \
    SM = fmaxf(__builtin_fmaf(-PETm, ef, SM3), HBV_NZ);                        \
    /* ---- off-chain: SUZ/SLZ/Q ---- */                                       \
    float U_ = __builtin_fmaf(rt, sw, SM1 - SM2);   /* recharge+excess */      \
    float S_ = SUZ + U_;                                                       \
    float P_ = fminf(S_, parPERC);                                             \
    float A_ = S_ - P_;                                                        \
    float B_ = fminf(A_, __builtin_fmaf(K0c, A_, K0UZL));                      \
    SUZ = K1c * B_;                                                            \
    float L_ = SLZ - (SM3 - SM2) + P_;                                         \
    SLZ = K2c * L_;                                                            \
    (qdst)[(s) * 64] = __builtin_fmaf(parK2, L_, A_ - SUZ);                    \
} while (0)

// One 15-or-5-step sub-block: stage LDS -> registers, run steps.
#define SOIL_HALF(nn, ofs) do {                                                \
    const float* rs = &rtS[(ofs)];                                             \
    const float* es = &petS[(ofs)];                                            \
    float* qd = &qS[(ofs)];                                                    \
    float rr[15], pv[15];                                                      \
    _Pragma("unroll")                                                          \
    for (int k_ = 0; k_ < (nn); ++k_) {                                        \
        rr[k_] = rs[k_ * 64];                                                  \
        pv[k_] = es[k_ * 64];                                                  \
    }                                                                          \
    _Pragma("unroll")                                                          \
    for (int s_ = 0; s_ < (nn); ++s_) SOIL_STEP(s_, rr[s_], pv[s_], qd);       \
} while (0)

// ---- snow: forcing load + forcing-only recurrence -> rt, raw PET ----------
#define SNOW_HALF(nn, tb, ofs) do {                                            \
    float Pf[15], Tf[15], Ef[15];                                              \
    _Pragma("unroll")                                                          \
    for (int k_ = 0; k_ < (nn); ++k_) {                                        \
        F3 f = xb3[(size_t)((tb) + k_) * HBV_B];                               \
        Pf[k_] = f.x; Tf[k_] = f.y; Ef[k_] = f.z;                              \
    }                                                                          \
    float* rd = &rtS[(ofs)];                                                   \
    float* ed = &petS[(ofs)];                                                  \
    _Pragma("unroll")                                                          \
    for (int s_ = 0; s_ < (nn); ++s_) {                                        \
        float Pm = Pf[s_], Tc = Tf[s_];                                        \
        float rain = (Tc >= parTT) ? Pm : 0.0f;                                \
        SNW += Pm - rain;                                                      \
        float melt = fminf(fmaxf(__builtin_fmaf(parCFMAX, Tc, negCT), 0.0f),   \
                           SNW);                                               \
        MLT += melt; SNW -= melt;                                              \
        float rfz = fminf(fmaxf(__builtin_fmaf(-CFRC, Tc, CFRCTT), 0.0f),      \
                          MLT);                                                \
        SNW += rfz; MLT -= rfz;                                                \
        float tosoil = fmaxf(__builtin_fmaf(-parCWH, SNW, MLT), 0.0f);         \
        MLT -= tosoil;                                                         \
        rd[s_ * 64] = rain + tosoil;                                           \
        ed[s_ * 64] = Ef[s_];                                                  \
    }                                                                          \
} while (0)

// ---- route: LDS -> 15-tap FIR ring -> DPP mean over m -> store ------------
// (tb) is always a multiple of 15, so ring slot == local index s_.
#define ROUTE_HALF(nn, tb, ofs) do {                                           \
    const float* qsrc = &qS[(ofs)];                                            \
    float qq[15];                                                              \
    _Pragma("unroll")                                                          \
    for (int k_ = 0; k_ < (nn); ++k_) qq[k_] = qsrc[k_ * 64];                  \
    _Pragma("unroll")                                                          \
    for (int s_ = 0; s_ < (nn); ++s_) {                                        \
        q[s_] = qq[s_];                                                        \
        float qr = 0.0f;                                                       \
        _Pragma("unroll")                                                      \
        for (int k_ = 0; k_ < 15; ++k_)                                        \
            qr += w[k_] * q[(s_ - k_ + 15) % 15];                              \
        DPP_ADD_ROR(qr, 0x128);                                                \
        DPP_ADD_ROR(qr, 0x124);                                                \
        DPP_ADD_ROR(qr, 0x122);                                                \
        DPP_ADD_ROR(qr, 0x121);                                                \
        if (m == 0) out[(size_t)((tb) + s_) * HBV_B + b] = qr;                 \
    }                                                                          \
} while (0)

__global__ __launch_bounds__(256, 1)
void hbv_smt_kernel(const float* __restrict__ x_phy,   // (2000, 1024, 3)
                    const float* __restrict__ ps,      // (1024, 288)
                    float* __restrict__ out)           // (2000, 1024)
{
    const int lane = (int)threadIdx.x & 63;
    const int wv   = (int)threadIdx.x >> 6;   // 0 soil, 1 route, 2 snow, 3 idle
    const int b    = blockIdx.x * 4 + (lane >> 4);
    const int m    = lane & 15;

    __shared__ float rtS [2 * SBUF];  // snow -> soil : rain+tosoil
    __shared__ float petS[2 * SBUF];  // snow -> soil : raw PET
    __shared__ float qS  [2 * SBUF];  // soil -> route: Qsim
    // +36 KB dynamic LDS at launch pads the group segment past 80 KB so a
    // second block can never co-reside (keeps SIMD0 exclusively soil's).

    const float* __restrict__ pb = ps + (size_t)b * 288;

    if (wv == 0) {
        // --------------------------- SOIL (SIMD0) ---------------------------
        const float parBETA   = 1.0f   + pb[ 0*16 + m] * 5.0f;
        const float parFC     = 50.0f  + pb[ 1*16 + m] * 950.0f;
        const float parK0     = 0.05f  + pb[ 2*16 + m] * 0.85f;
        const float parK1     = 0.01f  + pb[ 3*16 + m] * 0.49f;
        const float parK2     = 0.001f + pb[ 4*16 + m] * 0.199f;
        const float parLP     = 0.2f   + pb[ 5*16 + m] * 0.8f;
        const float parPERC   =          pb[ 6*16 + m] * 10.0f;
        const float parUZL    =          pb[ 7*16 + m] * 100.0f;
        const float parBETAET = 0.3f   + pb[12*16 + m] * 4.7f;
        const float parC      =          pb[13*16 + m];
        const float invFC  = 1.0f / parFC;
        const float K0c    = 1.0f - parK0;
        const float K0UZL  = parK0 * parUZL;
        const float K1c    = 1.0f - parK1;
        const float K2c    = 1.0f - parK2;
        const float nBlogFC    = -parBETA   * __builtin_amdgcn_logf(parFC);
        const float nBEloglpfc = -parBETAET * __builtin_amdgcn_logf(parLP * parFC);

        float SM = HBV_NZ, SUZ = HBV_NZ, SLZ = HBV_NZ;

        __syncthreads();                                  // phase 0
#pragma unroll 1
        for (int sc = 0; sc < 66; ++sc) {                 // phases 1..66
            const int po = (sc & 1) * SBUF + lane;
            SOIL_HALF(15, po);
            SOIL_HALF(15, po + 15 * 64);
            __syncthreads();
        }
        // sc=66 (20 steps, parity 0): phase 67
        SOIL_HALF(15, lane);
        SOIL_HALF(5, lane + 15 * 64);
        __syncthreads();
        __syncthreads();                                  // phase 68
        // 69 barriers.
    } else if (wv == 2) {
        // --------------------------- SNOW (SIMD2) ---------------------------
        const float parTT    = -2.5f + pb[ 8*16 + m] * 5.0f;
        const float parCFMAX = 0.5f  + pb[ 9*16 + m] * 9.5f;
        const float parCFR   =         pb[10*16 + m] * 0.1f;
        const float parCWH   =         pb[11*16 + m] * 0.2f;
        const float CFRC   = parCFR * parCFMAX;
        const float negCT  = -parCFMAX * parTT;
        const float CFRCTT =  CFRC * parTT;
        float SNW = HBV_NZ, MLT = HBV_NZ;
        const F3* __restrict__ xb3 = (const F3*)x_phy + b;

#pragma unroll 1
        for (int sc = 0; sc < 66; ++sc) {                 // phases 0..65
            const int po = (sc & 1) * SBUF + lane;
            SNOW_HALF(15, sc * 30,      po);
            SNOW_HALF(15, sc * 30 + 15, po + 15 * 64);
            __syncthreads();
        }
        // sc=66: phase 66
        SNOW_HALF(15, 1980, lane);
        SNOW_HALF(5, 1995, lane + 15 * 64);
        __syncthreads();
        __syncthreads();                                  // phase 67
        __syncthreads();                                  // phase 68
        // 69 barriers.
    } else if (wv == 1) {
        // --------------------------- ROUTE (SIMD1) --------------------------
        const float rout_a = pb[256 + m]      * 2.9f;
        const float rout_b = pb[256 + 16 + m] * 6.5f;
        // w[k] ∝ t_k^(a-1) exp(-t_k/theta); Gamma/theta^a cancels under
        // normalization; pre-scaled by 1/16 for the mean over m.
        const float aa    = fmaxf(rout_a, 0.0f) + 0.1f;
        const float theta = fmaxf(rout_b, 0.0f) + 0.5f;
        const float am1   = aa - 1.0f;
        const float nit   = -1.4426950408889634f / theta;
        float w[15];
        float wsum = 0.0f;
#pragma unroll
        for (int k = 0; k < 15; ++k) {
            float tk = (float)k + 0.5f;
            float e  = am1 * __builtin_amdgcn_logf(tk) + nit * tk;
            w[k] = __builtin_amdgcn_exp2f(e);
            wsum += w[k];
        }
        const float wscale = 1.0f / (16.0f * wsum);
#pragma unroll
        for (int k = 0; k < 15; ++k) w[k] *= wscale;
        float q[15];
#pragma unroll
        for (int k = 0; k < 15; ++k) q[k] = 0.0f;

        __syncthreads();                                  // phase 0
        __syncthreads();                                  // phase 1
#pragma unroll 1
        for (int sc = 0; sc < 66; ++sc) {                 // phases 2..67
            const int po = (sc & 1) * SBUF + lane;
            ROUTE_HALF(15, sc * 30,      po);
            ROUTE_HALF(15, sc * 30 + 15, po + 15 * 64);
            __syncthreads();
        }
        // sc=66: phase 68
        ROUTE_HALF(15, 1980, lane);
        ROUTE_HALF(5, 1995, lane + 15 * 64);
        __syncthreads();
        // 69 barriers.
    } else {
        // --------------------------- IDLER (SIMD3) --------------------------
#pragma unroll 1
        for (int p = 0; p < 69; ++p) __syncthreads();
    }
}

extern "C" void kernel_launch(void* const* d_in, const int* in_sizes, int n_in,
                              void* d_out, int out_size, void* d_ws, size_t ws_size,
                              hipStream_t stream) {
    const float* x_phy = (const float*)d_in[0];   // (2000,1024,3) fp32
    const float* ps    = (const float*)d_in[1];   // (1024,288)    fp32
    float* out         = (float*)d_out;           // (2000,1024)   fp32

    // 256 blocks x 256 threads (4 waves, 1/SIMD), 1 block/CU (LDS-padded).
    // Wall = 2000 x soil chain (4 trans + 7 VALU); soil wave owns SIMD0.
    // 36 KB dynamic LDS: occupancy clamp only (46 KB static + 36 KB > 80 KB).
    hbv_smt_kernel<<<256, 256, 36 * 1024, stream>>>(x_phy, ps, out);
}